// Round 13
// baseline (659.771 us; speedup 1.0000x reference)
//
#include <hip/hip_runtime.h>
#include <hip/hip_bf16.h>
#include <stdint.h>

// Q8_0 dequant linear: y = x @ W^T + bias.  M=N=K=4096.
// INT8 path, ANTI-PHASE WAVES: 256x256 tile, BK=64, A x4 + B x4 buffers
// (128 KiB LDS), stage 3 tiles ahead. Waves 0-3 (one per SIMD): read
// frags(t) then MFMA(t). Waves 4-7 (second wave per SIMD): MFMA(t) on
// frags read last tile, then read frags(t+1). Each SIMD keeps its matrix
// pipe busy while the partner wave reads. One lgkm(0)+vmcnt(4)+barrier
// per tile. XOR-swizzled LDS, hoisted imm-offset read bases.

#define M_DIM 4096
#define N_DIM 4096
#define K_DIM 4096
#define NB_SC 128

#define BM 256
#define BN 256
#define BKB 64                   // K-tile bytes (= elements, i8)
#define NT (K_DIM / BKB)         // 64 K-tiles
#define TILE 16384               // 256 rows x 64 B per tile buffer

typedef __attribute__((ext_vector_type(4))) int i32x4;

__device__ __forceinline__ void gload_lds16(const void* gsrc, void* ldsdst) {
  __builtin_amdgcn_global_load_lds(
      (__attribute__((address_space(1))) void*)(uintptr_t)gsrc,
      (__attribute__((address_space(3))) void*)(uint32_t)(uintptr_t)ldsdst,
      16, 0, 0);
}

__device__ __forceinline__ int pack4(int a, int b, int c, int d) {
  return (a & 255) | ((b & 255) << 8) | ((c & 255) << 16) | ((d & 255) << 24);
}

// ---------------- fused prep kernel (unchanged, verified) ----------------

__global__ void prep_kernel(const float* __restrict__ x, const int* __restrict__ q,
                            const float* __restrict__ sc,
                            char* __restrict__ xb, char* __restrict__ wb,
                            float* __restrict__ sxv, float* __restrict__ swv) {
  __shared__ float red[4];
  const int b = blockIdx.x;
  const int t = threadIdx.x;
  if (b < 4096) {
    const float4* row = (const float4*)(x + (size_t)b * K_DIM);
    float4 v[4];
    float m = 0.f;
#pragma unroll
    for (int i = 0; i < 4; ++i) {
      v[i] = row[t * 4 + i];
      m = fmaxf(m, fmaxf(fmaxf(fabsf(v[i].x), fabsf(v[i].y)),
                         fmaxf(fabsf(v[i].z), fabsf(v[i].w))));
    }
#pragma unroll
    for (int off = 32; off >= 1; off >>= 1) m = fmaxf(m, __shfl_xor(m, off, 64));
    if ((t & 63) == 0) red[t >> 6] = m;
    __syncthreads();
    m = fmaxf(fmaxf(red[0], red[1]), fmaxf(red[2], red[3]));
    const float inv = (m > 0.f) ? 127.0f / m : 0.f;
    int4 o;
    o.x = pack4(__float2int_rn(v[0].x * inv), __float2int_rn(v[0].y * inv),
                __float2int_rn(v[0].z * inv), __float2int_rn(v[0].w * inv));
    o.y = pack4(__float2int_rn(v[1].x * inv), __float2int_rn(v[1].y * inv),
                __float2int_rn(v[1].z * inv), __float2int_rn(v[1].w * inv));
    o.z = pack4(__float2int_rn(v[2].x * inv), __float2int_rn(v[2].y * inv),
                __float2int_rn(v[2].z * inv), __float2int_rn(v[2].w * inv));
    o.w = pack4(__float2int_rn(v[3].x * inv), __float2int_rn(v[3].y * inv),
                __float2int_rn(v[3].z * inv), __float2int_rn(v[3].w * inv));
    ((int4*)(xb + (size_t)b * K_DIM))[t] = o;
    if (t == 0) sxv[b] = m / 127.0f;
  } else {
    const int o_row = b - 4096;
    float m = sc[o_row * NB_SC + (t & 127)];
#pragma unroll
    for (int off = 32; off >= 1; off >>= 1) m = fmaxf(m, __shfl_xor(m, off, 64));
    if ((t & 63) == 0) red[t >> 6] = m;
    __syncthreads();
    m = fmaxf(fmaxf(red[0], red[1]), fmaxf(red[2], red[3]));
    const float ratio = sc[o_row * NB_SC + (t >> 1)] / m;   // scales >= 1e-4 > 0
    const int4* qp = (const int4*)(q + (size_t)o_row * K_DIM);
    int4 qv[4];
#pragma unroll
    for (int i = 0; i < 4; ++i) qv[i] = qp[t * 4 + i];
    int4 ov;
    ov.x = pack4(__float2int_rn((float)qv[0].x * ratio), __float2int_rn((float)qv[0].y * ratio),
                 __float2int_rn((float)qv[0].z * ratio), __float2int_rn((float)qv[0].w * ratio));
    ov.y = pack4(__float2int_rn((float)qv[1].x * ratio), __float2int_rn((float)qv[1].y * ratio),
                 __float2int_rn((float)qv[1].z * ratio), __float2int_rn((float)qv[1].w * ratio));
    ov.z = pack4(__float2int_rn((float)qv[2].x * ratio), __float2int_rn((float)qv[2].y * ratio),
                 __float2int_rn((float)qv[2].z * ratio), __float2int_rn((float)qv[2].w * ratio));
    ov.w = pack4(__float2int_rn((float)qv[3].x * ratio), __float2int_rn((float)qv[3].y * ratio),
                 __float2int_rn((float)qv[3].z * ratio), __float2int_rn((float)qv[3].w * ratio));
    ((int4*)(wb + (size_t)o_row * K_DIM))[t] = ov;
    if (t == 0) swv[o_row] = m;
  }
}

// ---------------- 256x256 BK=64 i8 GEMM, anti-phase waves ----------------
// LDS rows 64 B = 4 x 16B granules. Logical granule g of row r stored at
// g ^ s(r), s(r) = (r&3)^((r>>2)&3) (involution; invariant under +16 rows ->
// hoisted read bases with immediate offsets).

// Stage one K-tile of A and B 3 tiles ahead: per wave 2+2 gloads of 1 KiB
// (16 rows each); wave w covers rows [w*32, w*32+32).
__device__ __forceinline__ void stage_tile(const char* __restrict__ pA,
                                           const char* __restrict__ pB,
                                           char* As, char* Bs,
                                           int bufw, int ktb, int w) {
#pragma unroll
  for (int j = 0; j < 2; ++j)
    gload_lds16(pA + (size_t)(16 * j) * K_DIM + ktb,
                As + bufw * TILE + w * 2048 + j * 1024);
#pragma unroll
  for (int j = 0; j < 2; ++j)
    gload_lds16(pB + (size_t)(16 * j) * K_DIM + ktb,
                Bs + bufw * TILE + w * 2048 + j * 1024);
}

// fr[0..7] = A frags (8 x 16 rows), fr[8..11] = B frags (4 x 16 rows)
template <int BUF>
__device__ __forceinline__ void read12(const char* pa, const char* pb,
                                       i32x4 (&fr)[12]) {
#pragma unroll
  for (int n = 0; n < 4; ++n)
    fr[8 + n] = *(const i32x4*)(pb + BUF * TILE + n * 1024);
#pragma unroll
  for (int m = 0; m < 8; ++m)
    fr[m] = *(const i32x4*)(pa + BUF * TILE + m * 1024);
}

__device__ __forceinline__ void mfma32(const i32x4 (&fr)[12], i32x4 (&acc)[8][4]) {
  __builtin_amdgcn_s_setprio(1);
#pragma unroll
  for (int m = 0; m < 8; ++m)
#pragma unroll
    for (int n = 0; n < 4; ++n)
      acc[m][n] = __builtin_amdgcn_mfma_i32_16x16x64_i8(fr[m], fr[8 + n], acc[m][n], 0, 0, 0);
  __builtin_amdgcn_s_setprio(0);
}

// MODE: 0 = steady (stage t+3, vmcnt(4)); 1 = t==NT-3 (no stage, vmcnt(0));
//       2 = t==NT-2 (no stage, no vmcnt, late waves still read t+1);
//       3 = t==NT-1 (final: no boundary, no read-ahead)
template <int BUF, int MODE>
__device__ __forceinline__ void ktile(const char* pa, const char* pb,
                                      const char* __restrict__ pA,
                                      const char* __restrict__ pB,
                                      char* As, char* Bs, int ktb, int w, bool late,
                                      i32x4 (&fr)[12], i32x4 (&acc)[8][4]) {
  if (MODE == 0)
    stage_tile(pA, pB, As, Bs, (BUF + 3) & 3, ktb + 3 * BKB, w);
  if (!late) {
    // early wave: read current tile, then MFMA (counted lgkm overlaps)
    read12<BUF>(pa, pb, fr);
    mfma32(fr, acc);
  } else {
    // late wave: MFMA on frags read last tile, THEN read next tile
    mfma32(fr, acc);
    __builtin_amdgcn_sched_barrier(0);   // pin: reads must not hoist above MFMAs
    if (MODE < 3) read12<(BUF + 1) & 3>(pa, pb, fr);
  }
  if (MODE < 3) {
    asm volatile("s_waitcnt lgkmcnt(0)" ::: "memory");
    if (MODE == 0)
      asm volatile("s_waitcnt vmcnt(4)" ::: "memory");  // t+2 landed; t+3 in flight
    else if (MODE == 1)
      asm volatile("s_waitcnt vmcnt(0)" ::: "memory");
    __builtin_amdgcn_s_barrier();
    __builtin_amdgcn_sched_barrier(0);
  }
}

__global__ __launch_bounds__(512, 2) void gemm256(const char* __restrict__ A,
                                                  const char* __restrict__ B,
                                                  const float* __restrict__ sxv,
                                                  const float* __restrict__ swv,
                                                  const float* __restrict__ bias,
                                                  float* __restrict__ C) {
  __shared__ char As[4 * TILE];   // 64 KiB (A quad buffer)
  __shared__ char Bs[4 * TILE];   // 64 KiB (B quad buffer)

  const int tid = threadIdx.x;
  const int w = tid >> 6;
  const int l = tid & 63;
  const int wm = w >> 2;            // waves 0-3 / 4-7: wm 0/1 -> anti-phase pairs
  const int wn = w & 3;
  const int frow = l & 15;
  const int gl = l >> 4;
  const bool late = ((w >> 2) & 1) != 0;

  const int bid = blockIdx.x;
  const int cpx = gridDim.x >> 3;   // 256 % 8 == 0 -> bijective
  const int swz = (bid & 7) * cpx + (bid >> 3);
  const int bm0 = (swz >> 4) * BM;
  const int bn0 = (swz & 15) * BN;

  // hoisted lane-constant LDS read bases
  const int srow = (frow & 3) ^ ((frow >> 2) & 3);
  const int swg = (gl ^ srow) << 4;
  const char* pa = (const char*)As + (wm * 128 + frow) * 64 + swg;
  const char* pb = (const char*)Bs + (wn * 64 + frow) * 64 + swg;

  // lane-constant global stage bases (pre-swizzled source granule)
  const int sr = l >> 2;
  const int g1 = (l & 3) ^ ((l >> 2) & 3);
  const int skp = (g1 ^ ((l >> 4) & 3)) << 4;
  const char* pA = A + (size_t)(bm0 + w * 32 + sr) * K_DIM + skp;
  const char* pB = B + (size_t)(bn0 + w * 32 + sr) * K_DIM + skp;

  i32x4 acc[8][4] = {};
  i32x4 fr[12];

  // Prologue: stage tiles 0,1,2 -> bufs 0,1,2 (12 gloads/wave);
  // vmcnt(4): tiles 0,1 landed, tile 2 in flight (steady invariant).
#pragma unroll
  for (int tt = 0; tt < 3; ++tt)
    stage_tile(pA, pB, As, Bs, tt, tt * BKB, w);
  asm volatile("s_waitcnt vmcnt(4)" ::: "memory");
  __builtin_amdgcn_s_barrier();
  if (late) read12<0>(pa, pb, fr);   // late waves pre-read tile 0

  for (int t = 0; t < NT - 4; t += 4) {
    ktile<0, 0>(pa, pb, pA, pB, As, Bs, (t + 0) * BKB, w, late, fr, acc);
    ktile<1, 0>(pa, pb, pA, pB, As, Bs, (t + 1) * BKB, w, late, fr, acc);
    ktile<2, 0>(pa, pb, pA, pB, As, Bs, (t + 2) * BKB, w, late, fr, acc);
    ktile<3, 0>(pa, pb, pA, pB, As, Bs, (t + 3) * BKB, w, late, fr, acc);
  }
  ktile<0, 0>(pa, pb, pA, pB, As, Bs, (NT - 4) * BKB, w, late, fr, acc);
  ktile<1, 1>(pa, pb, pA, pB, As, Bs, (NT - 3) * BKB, w, late, fr, acc);
  ktile<2, 2>(pa, pb, pA, pB, As, Bs, (NT - 2) * BKB, w, late, fr, acc);
  ktile<3, 3>(pa, pb, pA, pB, As, Bs, (NT - 1) * BKB, w, late, fr, acc);

  // Epilogue: y = s_x[m]*s_w[n]*acc + bias[n]; C/D col=l&15, row=(l>>4)*4+r
#pragma unroll
  for (int ni = 0; ni < 4; ++ni) {
    const int n = bn0 + wn * 64 + ni * 16 + (l & 15);
    const float swn = swv[n];
    const float bv = bias[n];
#pragma unroll
    for (int mi = 0; mi < 8; ++mi) {
      const int mbase = bm0 + wm * 128 + mi * 16 + (l >> 4) * 4;
#pragma unroll
      for (int r = 0; r < 4; ++r)
        C[(size_t)(mbase + r) * N_DIM + n] =
            (float)acc[mi][ni][r] * (swn * sxv[mbase + r]) + bv;
    }
  }
}

// ---------------- naive fallback ----------------

__global__ void naive_kernel(const float* __restrict__ x, const int* __restrict__ q,
                             const float* __restrict__ sc, const float* __restrict__ bias,
                             float* __restrict__ out) {
  size_t idx = (size_t)blockIdx.x * blockDim.x + threadIdx.x;
  if (idx >= (size_t)M_DIM * N_DIM) return;
  int n = (int)(idx & (N_DIM - 1));
  size_t m = idx >> 12;
  float acc = 0.f;
  for (int k = 0; k < K_DIM; k += 32) {
    float s = sc[n * NB_SC + (k >> 5)];
    float part = 0.f;
    for (int j = 0; j < 32; ++j)
      part += x[m * K_DIM + k + j] * (float)q[(size_t)n * K_DIM + k + j];
    acc += part * s;
  }
  out[idx] = acc + bias[n];
}

// ---------------- launch ----------------

extern "C" void kernel_launch(void* const* d_in, const int* in_sizes, int n_in,
                              void* d_out, int out_size, void* d_ws, size_t ws_size,
                              hipStream_t stream) {
  const float* x    = (const float*)d_in[0];
  const int*   q    = (const int*)d_in[1];
  const float* sc   = (const float*)d_in[2];
  const float* bias = (const float*)d_in[3];
  float* out = (float*)d_out;

  const size_t elems = (size_t)M_DIM * K_DIM;
  const size_t need  = 2 * elems + 2 * 4096 * sizeof(float);

  if (ws_size >= need) {
    char* xb = (char*)d_ws;
    char* wb = xb + elems;
    float* sxv = (float*)(wb + elems);
    float* swv = sxv + 4096;
    hipLaunchKernelGGL(prep_kernel, dim3(8192), dim3(256), 0, stream,
                       x, q, sc, xb, wb, sxv, swv);
    hipLaunchKernelGGL(gemm256, dim3((M_DIM / BM) * (N_DIM / BN)), dim3(512), 0, stream,
                       xb, wb, sxv, swv, bias, out);
  } else {
    hipLaunchKernelGGL(naive_kernel, dim3((M_DIM * N_DIM) / 256), dim3(256), 0, stream,
                       x, q, sc, bias, out);
  }
}

// Round 14
// 90.855 us; speedup vs baseline: 7.2618x; 7.2618x over previous
//
#include <hip/hip_runtime.h>
#include <hip/hip_bf16.h>
#include <stdint.h>

// Q8_0 dequant linear: y = x @ W^T + bias.  M=N=K=4096.
// INT8 path (round-7 best: 91.5 us total, GEMM 70.5 us, absmax 3.5):
// prep quantizes x per-row to i8 (s_x) and requantizes W per-row
// (s_w = max block scale); 256x256-tile BK=128 i8 MFMA GEMM
// (mfma_i32_16x16x64_i8, 2x bf16 rate, half traffic), 4 phases/K-tile,
// 1 barrier/phase, reads-one-quad-ahead, sched_barrier, counted vmcnt,
// XOR-swizzled LDS (0 conflicts); epilogue y = s_x[m]*s_w[n]*acc + bias[n].

#define M_DIM 4096
#define N_DIM 4096
#define K_DIM 4096
#define NB_SC 128

#define BM 256
#define BN 256
#define BKB 128                  // K-tile in bytes (= elements, i8)
#define NT (K_DIM / BKB)         // 32 K-tiles
#define TILE_B (BM * BKB)        // 32 KiB per tile buffer

typedef __attribute__((ext_vector_type(4))) int i32x4;

__device__ __forceinline__ void gload_lds16(const void* gsrc, void* ldsdst) {
  __builtin_amdgcn_global_load_lds(
      (__attribute__((address_space(1))) void*)(uintptr_t)gsrc,
      (__attribute__((address_space(3))) void*)(uint32_t)(uintptr_t)ldsdst,
      16, 0, 0);
}

__device__ __forceinline__ int pack4(int a, int b, int c, int d) {
  return (a & 255) | ((b & 255) << 8) | ((c & 255) << 16) | ((d & 255) << 24);
}

// ---------------- fused prep kernel ----------------
// blocks [0,4096): quantize x row b;  blocks [4096,8192): requantize W row b-4096.

__global__ void prep_kernel(const float* __restrict__ x, const int* __restrict__ q,
                            const float* __restrict__ sc,
                            char* __restrict__ xb, char* __restrict__ wb,
                            float* __restrict__ sxv, float* __restrict__ swv) {
  __shared__ float red[4];
  const int b = blockIdx.x;
  const int t = threadIdx.x;
  if (b < 4096) {
    const float4* row = (const float4*)(x + (size_t)b * K_DIM);
    float4 v[4];
    float m = 0.f;
#pragma unroll
    for (int i = 0; i < 4; ++i) {
      v[i] = row[t * 4 + i];
      m = fmaxf(m, fmaxf(fmaxf(fabsf(v[i].x), fabsf(v[i].y)),
                         fmaxf(fabsf(v[i].z), fabsf(v[i].w))));
    }
#pragma unroll
    for (int off = 32; off >= 1; off >>= 1) m = fmaxf(m, __shfl_xor(m, off, 64));
    if ((t & 63) == 0) red[t >> 6] = m;
    __syncthreads();
    m = fmaxf(fmaxf(red[0], red[1]), fmaxf(red[2], red[3]));
    const float inv = (m > 0.f) ? 127.0f / m : 0.f;
    int4 o;
    o.x = pack4(__float2int_rn(v[0].x * inv), __float2int_rn(v[0].y * inv),
                __float2int_rn(v[0].z * inv), __float2int_rn(v[0].w * inv));
    o.y = pack4(__float2int_rn(v[1].x * inv), __float2int_rn(v[1].y * inv),
                __float2int_rn(v[1].z * inv), __float2int_rn(v[1].w * inv));
    o.z = pack4(__float2int_rn(v[2].x * inv), __float2int_rn(v[2].y * inv),
                __float2int_rn(v[2].z * inv), __float2int_rn(v[2].w * inv));
    o.w = pack4(__float2int_rn(v[3].x * inv), __float2int_rn(v[3].y * inv),
                __float2int_rn(v[3].z * inv), __float2int_rn(v[3].w * inv));
    ((int4*)(xb + (size_t)b * K_DIM))[t] = o;
    if (t == 0) sxv[b] = m / 127.0f;
  } else {
    const int o_row = b - 4096;
    float m = sc[o_row * NB_SC + (t & 127)];
#pragma unroll
    for (int off = 32; off >= 1; off >>= 1) m = fmaxf(m, __shfl_xor(m, off, 64));
    if ((t & 63) == 0) red[t >> 6] = m;
    __syncthreads();
    m = fmaxf(fmaxf(red[0], red[1]), fmaxf(red[2], red[3]));
    const float ratio = sc[o_row * NB_SC + (t >> 1)] / m;   // scales >= 1e-4 > 0
    const int4* qp = (const int4*)(q + (size_t)o_row * K_DIM);
    int4 qv[4];
#pragma unroll
    for (int i = 0; i < 4; ++i) qv[i] = qp[t * 4 + i];
    int4 ov;
    ov.x = pack4(__float2int_rn((float)qv[0].x * ratio), __float2int_rn((float)qv[0].y * ratio),
                 __float2int_rn((float)qv[0].z * ratio), __float2int_rn((float)qv[0].w * ratio));
    ov.y = pack4(__float2int_rn((float)qv[1].x * ratio), __float2int_rn((float)qv[1].y * ratio),
                 __float2int_rn((float)qv[1].z * ratio), __float2int_rn((float)qv[1].w * ratio));
    ov.z = pack4(__float2int_rn((float)qv[2].x * ratio), __float2int_rn((float)qv[2].y * ratio),
                 __float2int_rn((float)qv[2].z * ratio), __float2int_rn((float)qv[2].w * ratio));
    ov.w = pack4(__float2int_rn((float)qv[3].x * ratio), __float2int_rn((float)qv[3].y * ratio),
                 __float2int_rn((float)qv[3].z * ratio), __float2int_rn((float)qv[3].w * ratio));
    ((int4*)(wb + (size_t)o_row * K_DIM))[t] = ov;
    if (t == 0) swv[o_row] = m;
  }
}

// ---------------- 256x256 BK=128 i8 GEMM ----------------
// LDS tile [256][128] i8, 128B rows = 8 x 16B granules. Logical granule g of
// row r stored at granule g^(r&7); gload_lds dest linear, source pre-permuted.

__device__ __forceinline__ i32x4 lds_frag(const char* t, int r, int kb) {
  return *(const i32x4*)(t + r * BKB + ((((kb) >> 4) ^ (r & 7)) << 4));
}

__device__ __forceinline__ void stage_half(const char* __restrict__ pX,
                                           char* lds, int hr0, int ktb, int w) {
#pragma unroll
  for (int j = 0; j < 2; ++j) {
    gload_lds16(pX + (size_t)(hr0 + j * 8) * K_DIM + ktb,
                lds + (hr0 + w * 16 + j * 8) * BKB);
  }
}

__device__ __forceinline__ void read_a(const char* Ac, int r0, int frow, int fkb,
                                       i32x4 (&af)[2][2]) {
#pragma unroll
  for (int q = 0; q < 2; ++q)
#pragma unroll
    for (int kk = 0; kk < 2; ++kk)
      af[q][kk] = lds_frag(Ac, r0 + q * 16 + frow, kk * 64 + fkb);
}

__device__ __forceinline__ void read_b(const char* Bc, int wn, int frow, int fkb,
                                       i32x4 (&bf)[4][2]) {
#pragma unroll
  for (int ni = 0; ni < 4; ++ni)
#pragma unroll
    for (int kk = 0; kk < 2; ++kk)
      bf[ni][kk] = lds_frag(Bc, wn * 64 + ni * 16 + frow, kk * 64 + fkb);
}

__device__ __forceinline__ void mfma_quad(const i32x4 (&af)[2][2], const i32x4 (&bf)[4][2],
                                          i32x4 (&acc)[8][4], int q0) {
  __builtin_amdgcn_s_setprio(1);
#pragma unroll
  for (int q = 0; q < 2; ++q)
#pragma unroll
    for (int ni = 0; ni < 4; ++ni)
#pragma unroll
      for (int kk = 0; kk < 2; ++kk)
        acc[q0 + q][ni] =
            __builtin_amdgcn_mfma_i32_16x16x64_i8(af[q][kk], bf[ni][kk], acc[q0 + q][ni], 0, 0, 0);
  __builtin_amdgcn_s_setprio(0);
}

// MODE: 0 = steady; 1 = t == NT-2 (A(t+1) stage only, vmcnt(0)); 2 = last tile
// Entering: bf_cur/a0_cur hold tile t's B-frags and quad-0 (issued last phase).
template <int BUF, int MODE>
__device__ __forceinline__ void ktile(const char* __restrict__ pA,
                                      const char* __restrict__ pB,
                                      char* AsB, char* BsB,
                                      int ktb, int w, int wm, int wn, int frow, int fkb,
                                      i32x4 (&acc)[8][4],
                                      i32x4 (&bf_cur)[4][2], i32x4 (&bf_nxt)[4][2],
                                      i32x4 (&a0_cur)[2][2], i32x4 (&a0_nxt)[2][2]) {
  const char* Ac = AsB + BUF * TILE_B;
  const char* An = AsB + (BUF ^ 1) * TILE_B;
  const char* Bn = BsB + (BUF ^ 1) * TILE_B;
  char* Anw = AsB + (BUF ^ 1) * TILE_B;
  char* Bw  = BsB + BUF * TILE_B;

  i32x4 a1[2][2], a2[2][2], a3[2][2];

  // p0: reads a1(t); stage A0+A1(t+1)->other buf; MFMA q0 (a1 stays in flight)
  read_a(Ac, wm * 128 + 32, frow, fkb, a1);
  if (MODE < 2) {
    stage_half(pA, Anw, 0, ktb + BKB, w);
    stage_half(pA, Anw, 128, ktb + BKB, w);
  }
  __builtin_amdgcn_sched_barrier(0);
  mfma_quad(a0_cur, bf_cur, acc, 0);
  __builtin_amdgcn_s_barrier();

  // p1: reads a2(t); stage B0(t+2)->cur buf; MFMA q1
  read_a(Ac, wm * 128 + 64, frow, fkb, a2);
  if (MODE == 0) stage_half(pB, Bw, 0, ktb + 2 * BKB, w);
  __builtin_amdgcn_sched_barrier(0);
  mfma_quad(a1, bf_cur, acc, 2);
  __builtin_amdgcn_s_barrier();

  // p2: reads a3(t); stage B1(t+2); MFMA q2
  read_a(Ac, wm * 128 + 96, frow, fkb, a3);
  if (MODE == 0) stage_half(pB, Bw, 128, ktb + 2 * BKB, w);
  __builtin_amdgcn_sched_barrier(0);
  mfma_quad(a2, bf_cur, acc, 4);
  __builtin_amdgcn_s_barrier();

  // p3: counted vmcnt (drains B(t+1)+A(t+1), leaves B(t+2) in flight);
  // read next tile's B-frags + quad-0; MFMA q3
  if (MODE == 0)
    asm volatile("s_waitcnt vmcnt(4)" ::: "memory");
  else if (MODE == 1)
    asm volatile("s_waitcnt vmcnt(0)" ::: "memory");
  if (MODE < 2) {
    read_b(Bn, wn, frow, fkb, bf_nxt);
    read_a(An, wm * 128 + 0, frow, fkb, a0_nxt);
  }
  __builtin_amdgcn_sched_barrier(0);
  mfma_quad(a3, bf_cur, acc, 6);
  __builtin_amdgcn_s_barrier();
}

__global__ __launch_bounds__(512, 2) void gemm256(const char* __restrict__ A,
                                                  const char* __restrict__ B,
                                                  const float* __restrict__ sxv,
                                                  const float* __restrict__ swv,
                                                  const float* __restrict__ bias,
                                                  float* __restrict__ C) {
  __shared__ char AsB[2 * TILE_B];   // 64 KiB
  __shared__ char BsB[2 * TILE_B];   // 64 KiB

  const int tid = threadIdx.x;
  const int w = tid >> 6;
  const int l = tid & 63;
  const int wm = w >> 2;
  const int wn = w & 3;
  const int frow = l & 15;
  const int fkb = (l >> 4) * 16;     // byte offset of lane's 16 i8 K-slice

  const int bid = blockIdx.x;
  const int cpx = gridDim.x >> 3;
  const int swz = (bid & 7) * cpx + (bid >> 3);
  const int bm0 = (swz >> 4) * BM;
  const int bn0 = (swz & 15) * BN;

  // lane-constant stage base pointers (pre-swizzled source granule)
  const int sr = l >> 3;
  const int skp = ((l & 7) ^ sr) << 4;
  const char* pA = A + (size_t)(bm0 + w * 16 + sr) * K_DIM + skp;
  const char* pB = B + (size_t)(bn0 + w * 16 + sr) * K_DIM + skp;

  i32x4 acc[8][4] = {};
  i32x4 bf0[4][2], bf1[4][2];
  i32x4 a00[2][2], a01[2][2];

  // Prologue: tile0 {B0,B1,A0,A1}, then B0,B1(tile1). vmcnt(4): tile0 landed.
  stage_half(pB, BsB, 0, 0, w);
  stage_half(pB, BsB, 128, 0, w);
  stage_half(pA, AsB, 0, 0, w);
  stage_half(pA, AsB, 128, 0, w);
  stage_half(pB, BsB + TILE_B, 0, BKB, w);
  stage_half(pB, BsB + TILE_B, 128, BKB, w);
  asm volatile("s_waitcnt vmcnt(4)" ::: "memory");
  __builtin_amdgcn_s_barrier();
  read_b(BsB, wn, frow, fkb, bf0);
  read_a(AsB, wm * 128 + 0, frow, fkb, a00);

  for (int t = 0; t < NT - 2; t += 2) {
    ktile<0, 0>(pA, pB, AsB, BsB, t * BKB, w, wm, wn, frow, fkb, acc, bf0, bf1, a00, a01);
    ktile<1, 0>(pA, pB, AsB, BsB, (t + 1) * BKB, w, wm, wn, frow, fkb, acc, bf1, bf0, a01, a00);
  }
  ktile<0, 1>(pA, pB, AsB, BsB, (NT - 2) * BKB, w, wm, wn, frow, fkb, acc, bf0, bf1, a00, a01);
  ktile<1, 2>(pA, pB, AsB, BsB, (NT - 1) * BKB, w, wm, wn, frow, fkb, acc, bf1, bf0, a01, a00);

  // Epilogue: y = s_x[m]*s_w[n]*acc + bias[n]; C/D col=l&15, row=(l>>4)*4+r
#pragma unroll
  for (int ni = 0; ni < 4; ++ni) {
    const int n = bn0 + wn * 64 + ni * 16 + (l & 15);
    const float swn = swv[n];
    const float bv = bias[n];
#pragma unroll
    for (int mi = 0; mi < 8; ++mi) {
      const int mbase = bm0 + wm * 128 + mi * 16 + (l >> 4) * 4;
#pragma unroll
      for (int r = 0; r < 4; ++r)
        C[(size_t)(mbase + r) * N_DIM + n] =
            (float)acc[mi][ni][r] * (swn * sxv[mbase + r]) + bv;
    }
  }
}

// ---------------- naive fallback ----------------

__global__ void naive_kernel(const float* __restrict__ x, const int* __restrict__ q,
                             const float* __restrict__ sc, const float* __restrict__ bias,
                             float* __restrict__ out) {
  size_t idx = (size_t)blockIdx.x * blockDim.x + threadIdx.x;
  if (idx >= (size_t)M_DIM * N_DIM) return;
  int n = (int)(idx & (N_DIM - 1));
  size_t m = idx >> 12;
  float acc = 0.f;
  for (int k = 0; k < K_DIM; k += 32) {
    float s = sc[n * NB_SC + (k >> 5)];
    float part = 0.f;
    for (int j = 0; j < 32; ++j)
      part += x[m * K_DIM + k + j] * (float)q[(size_t)n * K_DIM + k + j];
    acc += part * s;
  }
  out[idx] = acc + bias[n];
}

// ---------------- launch ----------------

extern "C" void kernel_launch(void* const* d_in, const int* in_sizes, int n_in,
                              void* d_out, int out_size, void* d_ws, size_t ws_size,
                              hipStream_t stream) {
  const float* x    = (const float*)d_in[0];
  const int*   q    = (const int*)d_in[1];
  const float* sc   = (const float*)d_in[2];
  const float* bias = (const float*)d_in[3];
  float* out = (float*)d_out;

  const size_t elems = (size_t)M_DIM * K_DIM;               // 16.8M
  const size_t need  = 2 * elems + 2 * 4096 * sizeof(float);  // ~32 MB + 32 KB

  if (ws_size >= need) {
    char* xb = (char*)d_ws;
    char* wb = xb + elems;
    float* sxv = (float*)(wb + elems);
    float* swv = sxv + 4096;
    hipLaunchKernelGGL(prep_kernel, dim3(8192), dim3(256), 0, stream,
                       x, q, sc, xb, wb, sxv, swv);
    hipLaunchKernelGGL(gemm256, dim3((M_DIM / BM) * (N_DIM / BN)), dim3(512), 0, stream,
                       xb, wb, sxv, swv, bias, out);
  } else {
    hipLaunchKernelGGL(naive_kernel, dim3((M_DIM * N_DIM) / 256), dim3(256), 0, stream,
                       x, q, sc, bias, out);
  }
}